// Round 3
// baseline (19484.322 us; speedup 1.0000x reference)
//
#include <hip/hip_runtime.h>
#include <hip/hip_cooperative_groups.h>
#include <float.h>
#include <math.h>

namespace cg = cooperative_groups;

#define H      1024     // LATENT
#define V      32000    // VOCAB
#define NCOND  64
#define NLIN   1024
#define ZCN    1088     // LIN + COND
#define NSTEP  128
#define NBLK   256
#define NTHR   1024
#define WPB    16       // waves per block
#define GWAVES (NBLK * WPB)   // 4096 waves total

#define DOT4(a,b) ((a).x*(b).x + (a).y*(b).y + (a).z*(b).z + (a).w*(b).w)

__device__ __forceinline__ float waveReduceSum(float v) {
#pragma unroll
    for (int off = 32; off > 0; off >>= 1)
        v += __shfl_down(v, off, 64);
    return v;
}

// Flag-array grid barrier. Each block release-publishes its OWN flag (no
// contended RMW); wave 0 polls all NBLK flags (4 per lane, relaxed agent
// loads). Monotonic targets within one launch; flags zeroed in the prologue
// before the (known-good) cg::sync. Cooperative launch => all blocks
// co-resident => spinning is deadlock-free.
__device__ __forceinline__ void gridBarrier(int* flags, int target) {
    // make this thread's prior global writes agent-visible
    __builtin_amdgcn_fence(__ATOMIC_RELEASE, "agent");
    __syncthreads();
    if (threadIdx.x == 0)
        __hip_atomic_store(&flags[blockIdx.x], target,
                           __ATOMIC_RELAXED, __HIP_MEMORY_SCOPE_AGENT);
    if (threadIdx.x < 64) {
        const int* p = flags + (threadIdx.x << 2);
        for (;;) {
            int a = __hip_atomic_load(p + 0, __ATOMIC_RELAXED, __HIP_MEMORY_SCOPE_AGENT);
            int b = __hip_atomic_load(p + 1, __ATOMIC_RELAXED, __HIP_MEMORY_SCOPE_AGENT);
            int c = __hip_atomic_load(p + 2, __ATOMIC_RELAXED, __HIP_MEMORY_SCOPE_AGENT);
            int d = __hip_atomic_load(p + 3, __ATOMIC_RELAXED, __HIP_MEMORY_SCOPE_AGENT);
            if (__all((a >= target) && (b >= target) && (c >= target) && (d >= target)))
                break;
            __builtin_amdgcn_s_sleep(1);
        }
    }
    __syncthreads();
    // make remote blocks' writes visible to this thread's subsequent reads
    __builtin_amdgcn_fence(__ATOMIC_ACQUIRE, "agent");
}

extern "C" __global__ void __launch_bounds__(NTHR)
decoder_kernel(const float* __restrict__ z, const float* __restrict__ cnd,
               const float* __restrict__ l1W, const float* __restrict__ l1b,
               const float* __restrict__ emb, const float* __restrict__ Wih,
               const float* __restrict__ Whh, const float* __restrict__ bih,
               const float* __restrict__ bhh, const float* __restrict__ fcW,
               const float* __restrict__ fcb, float* __restrict__ out,
               float* __restrict__ ws)
{
    cg::grid_group grid = cg::this_grid();

    // 128 KiB static weight cache: wave wv owns s_w[wv*2048 .. +2048):
    // first 1024 = its Wih row, next 1024 = its Whh row. Reused 128 steps.
    __shared__ __align__(16) float s_w[WPB * 2048];
    __shared__ __align__(16) float s_x[H];
    __shared__ __align__(16) float s_h[H];
    __shared__ float s_gate[WPB];
    __shared__ float s_cs[4];          // this block's 4 cell-state elements
    __shared__ float s_wval[WPB];
    __shared__ int   s_widx[WPB];
    __shared__ int   s_tok;

    const int tid  = threadIdx.x;
    const int lane = tid & 63;
    const int wv   = tid >> 6;
    const int bid  = blockIdx.x;
    const int gw   = (bid << 4) + wv;           // global wave id [0, 4096)

    float* ws_h    = ws;                        // H floats
    float* ws_bval = ws + H;                    // NBLK floats
    int*   ws_bidx = (int*)(ws + H + NBLK);     // NBLK ints
    int*   flags   = (int*)(ws + H + 2 * NBLK); // NBLK ints

    // Block owns h elements [4*bid, 4*bid+4). Wave wv handles gate (wv&3)
    // of element (wv>>2)  ->  row grow in Wih/Whh (PyTorch i,f,g,o order).
    const int elem = wv >> 2;
    const int gate = wv & 3;
    const int hj   = (bid << 2) + elem;
    const int grow = gate * H + hj;

    // ---------------- prologue ----------------
    if (tid == 0) flags[bid] = 0;

    // stage this wave's Wih/Whh rows into LDS
    {
        float4* myw = (float4*)(s_w + (wv << 11));
        const float4* wi = (const float4*)(Wih + (size_t)grow * H);
        const float4* wh = (const float4*)(Whh + (size_t)grow * H);
#pragma unroll
        for (int k = 0; k < 4; ++k) {
            myw[(k << 6) + lane]       = wi[(k << 6) + lane];
            myw[256 + (k << 6) + lane] = wh[(k << 6) + lane];
        }
    }
    const float gbias = bih[grow] + bhh[grow];

    // hoist this wave's fcb entries (its 8 fc rows are fixed across steps)
    float fb[8];
#pragma unroll
    for (int i = 0; i < 8; ++i) {
        int r = gw + i * GWAVES;
        fb[i] = fcb[r < V ? r : 0];
    }

    // h0 = l1_W @ [z;c] + l1_b   (first 1024 waves, one row each)
    if (gw < H) {
        const float* wr = l1W + (size_t)gw * ZCN;
        float acc = 0.f;
        for (int k = lane; k < ZCN; k += 64) {
            float zc = (k < NLIN) ? z[k] : cnd[k - NLIN];
            acc += wr[k] * zc;
        }
        acc = waveReduceSum(acc);
        if (lane == 0) ws_h[gw] = acc + l1b[gw];
    }
    grid.sync();   // known-good cg barrier publishes flags=0 and ws_h(h0)

    // init: h = h0, x = relu(emb[SOS=0]), c = 0
    s_h[tid] = ws_h[tid];
    {
        float e = emb[tid];
        s_x[tid] = e > 0.f ? e : 0.f;
    }
    if (tid < 4) s_cs[tid] = 0.f;
    __syncthreads();

    int bar = 0;
    for (int step = 0; step < NSTEP; ++step) {
        // ---- Phase A: 16 gate dots from LDS weights ----
        {
            const float4* myw = (const float4*)(s_w + (wv << 11));
            const float4* xv = (const float4*)s_x;
            const float4* hv = (const float4*)s_h;
            float acc = 0.f;
#pragma unroll
            for (int k = 0; k < 4; ++k) {
                const int idx = (k << 6) + lane;
                float4 a  = myw[idx];
                float4 x4 = xv[idx];
                acc += DOT4(a, x4);
                float4 a2 = myw[256 + idx];
                float4 h4 = hv[idx];
                acc += DOT4(a2, h4);
            }
            acc = waveReduceSum(acc);
            if (lane == 0) s_gate[wv] = acc + gbias;
        }
        __syncthreads();

        // ---- fused LSTM cell update for this block's 4 elements ----
        if (tid < 4) {
            float gi = s_gate[(tid << 2) + 0];
            float gf = s_gate[(tid << 2) + 1];
            float gg = s_gate[(tid << 2) + 2];
            float go = s_gate[(tid << 2) + 3];
            float i_ = 1.f / (1.f + expf(-gi));
            float f_ = 1.f / (1.f + expf(-gf));
            float g_ = tanhf(gg);
            float o_ = 1.f / (1.f + expf(-go));
            float cn = f_ * s_cs[tid] + i_ * g_;
            s_cs[tid] = cn;
            ws_h[(bid << 2) + tid] = o_ * tanhf(cn);   // publish h_{t+1} slice
        }
        gridBarrier(flags, ++bar);

        // ---- stage full h_{t+1} into LDS ----
        s_h[tid] = ws_h[tid];
        __syncthreads();

        // ---- Phase B: logits + argmax, 4 fc rows interleaved per wave ----
        {
            const float4* h4p = (const float4*)s_h;
            float4 hb[4];
            hb[0] = h4p[lane];
            hb[1] = h4p[64 + lane];
            hb[2] = h4p[128 + lane];
            hb[3] = h4p[192 + lane];
            float best = -FLT_MAX; int bbi = 0x7fffffff;
            float* outp = out + (size_t)step * V;

            {   // chunk 0: rows gw + {0,1,2,3}*GWAVES — all valid
                const int r = gw;
                const float4* p0 = (const float4*)(fcW + (size_t)r * H);
                const float4* p1 = p0 + (size_t)GWAVES * 256;
                const float4* p2 = p1 + (size_t)GWAVES * 256;
                const float4* p3 = p2 + (size_t)GWAVES * 256;
                float a0 = 0.f, a1 = 0.f, a2 = 0.f, a3 = 0.f;
#pragma unroll
                for (int k = 0; k < 4; ++k) {
                    const int idx = (k << 6) + lane;
                    a0 += DOT4(p0[idx], hb[k]);
                    a1 += DOT4(p1[idx], hb[k]);
                    a2 += DOT4(p2[idx], hb[k]);
                    a3 += DOT4(p3[idx], hb[k]);
                }
#pragma unroll
                for (int off = 32; off > 0; off >>= 1) {
                    a0 += __shfl_down(a0, off, 64);
                    a1 += __shfl_down(a1, off, 64);
                    a2 += __shfl_down(a2, off, 64);
                    a3 += __shfl_down(a3, off, 64);
                }
                if (lane == 0) {
                    float lg;
                    lg = a0 + fb[0]; outp[r] = lg;
                    if (lg > best) { best = lg; bbi = r; }
                    lg = a1 + fb[1]; outp[r + GWAVES] = lg;
                    if (lg > best) { best = lg; bbi = r + GWAVES; }
                    lg = a2 + fb[2]; outp[r + 2*GWAVES] = lg;
                    if (lg > best) { best = lg; bbi = r + 2*GWAVES; }
                    lg = a3 + fb[3]; outp[r + 3*GWAVES] = lg;
                    if (lg > best) { best = lg; bbi = r + 3*GWAVES; }
                }
            }
            {   // chunk 1: rows gw + {4,5,6,7}*GWAVES — slot 7 may be OOB
                const int r  = gw + 4 * GWAVES;
                const int r3 = r + 3 * GWAVES;
                const bool v3 = (r3 < V);
                const float4* p0 = (const float4*)(fcW + (size_t)r * H);
                const float4* p1 = p0 + (size_t)GWAVES * 256;
                const float4* p2 = p1 + (size_t)GWAVES * 256;
                const float4* p3 = (const float4*)(fcW + (size_t)(v3 ? r3 : 0) * H);
                float a0 = 0.f, a1 = 0.f, a2 = 0.f, a3 = 0.f;
#pragma unroll
                for (int k = 0; k < 4; ++k) {
                    const int idx = (k << 6) + lane;
                    a0 += DOT4(p0[idx], hb[k]);
                    a1 += DOT4(p1[idx], hb[k]);
                    a2 += DOT4(p2[idx], hb[k]);
                    a3 += DOT4(p3[idx], hb[k]);
                }
#pragma unroll
                for (int off = 32; off > 0; off >>= 1) {
                    a0 += __shfl_down(a0, off, 64);
                    a1 += __shfl_down(a1, off, 64);
                    a2 += __shfl_down(a2, off, 64);
                    a3 += __shfl_down(a3, off, 64);
                }
                if (lane == 0) {
                    float lg;
                    lg = a0 + fb[4]; outp[r] = lg;
                    if (lg > best) { best = lg; bbi = r; }
                    lg = a1 + fb[5]; outp[r + GWAVES] = lg;
                    if (lg > best) { best = lg; bbi = r + GWAVES; }
                    lg = a2 + fb[6]; outp[r + 2*GWAVES] = lg;
                    if (lg > best) { best = lg; bbi = r + 2*GWAVES; }
                    if (v3) {
                        lg = a3 + fb[7]; outp[r3] = lg;
                        if (lg > best) { best = lg; bbi = r3; }
                    }
                }
            }
            if (lane == 0) { s_wval[wv] = best; s_widx[wv] = bbi; }
        }
        __syncthreads();
        if (tid == 0) {
            float bv = -FLT_MAX; int bi = 0x7fffffff;
#pragma unroll
            for (int w = 0; w < WPB; ++w) {
                float v = s_wval[w]; int id = s_widx[w];
                if (v > bv || (v == bv && id < bi)) { bv = v; bi = id; }
            }
            ws_bval[bid] = bv;
            ws_bidx[bid] = bi;
        }
        gridBarrier(flags, ++bar);

        // ---- token select (redundant per block) + stage next x ----
        if (wv == 0) {
            const int base = lane << 2;
            float bv = -FLT_MAX; int bi = 0x7fffffff;
#pragma unroll
            for (int k = 0; k < 4; ++k) {
                float v = ws_bval[base + k]; int id = ws_bidx[base + k];
                if (v > bv || (v == bv && id < bi)) { bv = v; bi = id; }
            }
#pragma unroll
            for (int off = 32; off > 0; off >>= 1) {
                float ov = __shfl_down(bv, off, 64);
                int   oi = __shfl_down(bi, off, 64);
                if (ov > bv || (ov == bv && oi < bi)) { bv = ov; bi = oi; }
            }
            if (lane == 0) s_tok = bi;
        }
        __syncthreads();
        {
            const float* er = emb + (size_t)s_tok * H;
            float e = er[tid];
            s_x[tid] = e > 0.f ? e : 0.f;
        }
        __syncthreads();
    }
}

extern "C" void kernel_launch(void* const* d_in, const int* in_sizes, int n_in,
                              void* d_out, int out_size, void* d_ws, size_t ws_size,
                              hipStream_t stream) {
    const float* z   = (const float*)d_in[0];
    const float* c   = (const float*)d_in[1];
    const float* l1W = (const float*)d_in[2];
    const float* l1b = (const float*)d_in[3];
    const float* emb = (const float*)d_in[4];
    const float* Wih = (const float*)d_in[5];
    const float* Whh = (const float*)d_in[6];
    const float* bih = (const float*)d_in[7];
    const float* bhh = (const float*)d_in[8];
    const float* fcW = (const float*)d_in[9];
    const float* fcb = (const float*)d_in[10];
    float* out = (float*)d_out;
    float* ws  = (float*)d_ws;

    void* args[] = { &z, &c, &l1W, &l1b, &emb, &Wih, &Whh, &bih, &bhh,
                     &fcW, &fcb, &out, &ws };
    hipLaunchCooperativeKernel((void*)decoder_kernel, dim3(NBLK), dim3(NTHR),
                               args, 0, stream);
}

// Round 6
// 4714.194 us; speedup vs baseline: 4.1331x; 4.1331x over previous
//
#include <hip/hip_runtime.h>
#include <float.h>
#include <math.h>

#define H      1024     // LATENT
#define V      32000    // VOCAB
#define NCOND  64
#define NLIN   1024
#define ZCN    1088     // LIN + COND
#define NSTEP  128

#define A_BLK  256      // stepA: 256 blocks x 1024 thr = 4096 waves (one per gate row)
#define B_BLK  512      // stepB: 512 blocks x 1024 thr = 8192 waves (4 fc rows each)
#define NTHR   1024
#define P_BLK  64       // prologue: 64 blocks x 1024 thr = 1024 waves (one per h0 row)

#define DOT4(a,b) ((a).x*(b).x + (a).y*(b).y + (a).z*(b).z + (a).w*(b).w)

// ws layout (floats):
//   [0,   H)    hbuf0
//   [H,  2H)    hbuf1          (h(t) lives in hbuf[t&1]; h0 -> hbuf1)
//   [2H, 3H)    cell state c
//   [3H, 3H+512)        pval   (per-block argmax val, stepB)
//   [3H+512, 3H+1024)   pidx   (int)

__device__ __forceinline__ float waveReduceSum(float v) {
#pragma unroll
    for (int off = 32; off > 0; off >>= 1)
        v += __shfl_down(v, off, 64);
    return v;
}

extern "C" __global__ void __launch_bounds__(NTHR)
k_prologue(const float* __restrict__ z, const float* __restrict__ cnd,
           const float* __restrict__ l1W, const float* __restrict__ l1b,
           float* __restrict__ ws)
{
    const int tid  = threadIdx.x;
    const int lane = tid & 63;
    const int wv   = tid >> 6;
    const int g    = blockIdx.x * 16 + wv;      // row in [0, 1024)

    float* hbuf1 = ws + H;
    float* cst   = ws + 2 * H;
    if (blockIdx.x == 0) cst[tid] = 0.f;        // zero cell state

    const float* wr = l1W + (size_t)g * ZCN;
    float acc = 0.f;
    for (int k = lane; k < ZCN; k += 64) {
        float zc = (k < NLIN) ? z[k] : cnd[k - NLIN];
        acc += wr[k] * zc;
    }
    acc = waveReduceSum(acc);
    if (lane == 0) hbuf1[g] = acc + l1b[g];
}

extern "C" __global__ void __launch_bounds__(NTHR)
k_stepA(const float* __restrict__ emb, const float* __restrict__ Wih,
        const float* __restrict__ Whh, const float* __restrict__ bih,
        const float* __restrict__ bhh, float* __restrict__ ws, int t)
{
    __shared__ __align__(16) float s_x[H];
    __shared__ __align__(16) float s_h[H];
    __shared__ float s_gate[16];
    __shared__ int   s_tok;

    const int tid  = threadIdx.x;
    const int lane = tid & 63;
    const int wv   = tid >> 6;
    const int bid  = blockIdx.x;

    float* hprev = ws + ((t & 1) ? 0 : H);      // h(t-1)   (h0 sits in hbuf1)
    float* hnew  = ws + ((t & 1) ? H : 0);      // h(t)
    float* cst   = ws + 2 * H;
    float* pval  = ws + 3 * H;
    int*   pidx  = (int*)(ws + 3 * H + B_BLK);

    // ---- token resolve (redundant per block; partials from stepB(t-1)) ----
    if (t == 0) {
        if (tid == 0) s_tok = 0;                // SOS
    } else if (wv == 0) {
        float bv = -FLT_MAX; int bi = 0x7fffffff;
        for (int k = lane; k < B_BLK; k += 64) {          // 8 entries/lane, ascending
            float v = pval[k]; int id = pidx[k];
            if (v > bv || (v == bv && id < bi)) { bv = v; bi = id; }
        }
#pragma unroll
        for (int off = 32; off > 0; off >>= 1) {
            float ov = __shfl_down(bv, off, 64);
            int   oi = __shfl_down(bi, off, 64);
            if (ov > bv || (ov == bv && oi < bi)) { bv = ov; bi = oi; }
        }
        if (lane == 0) s_tok = bi;
    }
    __syncthreads();

    // ---- stage x = relu(emb[tok]) and h(t-1) ----
    {
        const float* er = emb + (size_t)s_tok * H;
        float e = er[tid];
        s_x[tid] = e > 0.f ? e : 0.f;
        s_h[tid] = hprev[tid];
    }
    __syncthreads();

    // ---- 16 gate dots: block owns h elements [4*bid, 4*bid+4) ----
    const int elem = wv >> 2;
    const int gate = wv & 3;
    const int hj   = (bid << 2) + elem;
    const int grow = gate * H + hj;             // PyTorch i,f,g,o row order
    {
        const float4* wi = (const float4*)(Wih + (size_t)grow * H);
        const float4* wh = (const float4*)(Whh + (size_t)grow * H);
        const float4* xv = (const float4*)s_x;
        const float4* hv = (const float4*)s_h;
        float acc = 0.f;
#pragma unroll
        for (int k = 0; k < 4; ++k) {
            const int idx = (k << 6) + lane;
            float4 a  = wi[idx];
            float4 x4 = xv[idx];
            acc += DOT4(a, x4);
            float4 a2 = wh[idx];
            float4 h4 = hv[idx];
            acc += DOT4(a2, h4);
        }
        acc = waveReduceSum(acc);
        if (lane == 0) s_gate[wv] = acc + bih[grow] + bhh[grow];
    }
    __syncthreads();

    // ---- fused LSTM cell update for this block's 4 elements ----
    if (tid < 4) {
        float gi = s_gate[(tid << 2) + 0];
        float gf = s_gate[(tid << 2) + 1];
        float gg = s_gate[(tid << 2) + 2];
        float go = s_gate[(tid << 2) + 3];
        float i_ = 1.f / (1.f + expf(-gi));
        float f_ = 1.f / (1.f + expf(-gf));
        float g_ = tanhf(gg);
        float o_ = 1.f / (1.f + expf(-go));
        const int j = (bid << 2) + tid;
        float cn = f_ * cst[j] + i_ * g_;
        cst[j] = cn;
        hnew[j] = o_ * tanhf(cn);
    }
}

extern "C" __global__ void __launch_bounds__(NTHR)
k_stepB(const float* __restrict__ fcW, const float* __restrict__ fcb,
        float* __restrict__ ws, float* __restrict__ out, int t)
{
    __shared__ __align__(16) float s_h[H];
    __shared__ float s_wval[16];
    __shared__ int   s_widx[16];

    const int tid  = threadIdx.x;
    const int lane = tid & 63;
    const int wv   = tid >> 6;
    const int bid  = blockIdx.x;
    const int w    = bid * 16 + wv;             // wave id in [0, 8192)

    const float* hcur = ws + ((t & 1) ? H : 0); // h(t), written by stepA(t)
    float* pval = ws + 3 * H;
    int*   pidx = (int*)(ws + 3 * H + B_BLK);

    s_h[tid] = hcur[tid];
    __syncthreads();

    const float4* h4p = (const float4*)s_h;
    float4 hb[4];
    hb[0] = h4p[lane];
    hb[1] = h4p[64 + lane];
    hb[2] = h4p[128 + lane];
    hb[3] = h4p[192 + lane];

    float best = -FLT_MAX; int bbi = 0x7fffffff;
    float* outp = out + (size_t)t * V;

    // 4 fc rows per wave: r = w + k*8192, k<4; slot 3 may be OOB (V=32000)
    const int r0 = w;
    const int r1 = w + 8192;
    const int r2 = w + 16384;
    const int r3 = w + 24576;
    const bool v3 = (r3 < V);
    const float4* p0 = (const float4*)(fcW + (size_t)r0 * H);
    const float4* p1 = (const float4*)(fcW + (size_t)r1 * H);
    const float4* p2 = (const float4*)(fcW + (size_t)r2 * H);
    const float4* p3 = (const float4*)(fcW + (size_t)(v3 ? r3 : 0) * H);
    float a0 = 0.f, a1 = 0.f, a2 = 0.f, a3 = 0.f;
#pragma unroll
    for (int k = 0; k < 4; ++k) {
        const int idx = (k << 6) + lane;
        a0 += DOT4(p0[idx], hb[k]);
        a1 += DOT4(p1[idx], hb[k]);
        a2 += DOT4(p2[idx], hb[k]);
        a3 += DOT4(p3[idx], hb[k]);
    }
#pragma unroll
    for (int off = 32; off > 0; off >>= 1) {
        a0 += __shfl_down(a0, off, 64);
        a1 += __shfl_down(a1, off, 64);
        a2 += __shfl_down(a2, off, 64);
        a3 += __shfl_down(a3, off, 64);
    }
    if (lane == 0) {
        float lg;
        lg = a0 + fcb[r0]; outp[r0] = lg;
        if (lg > best) { best = lg; bbi = r0; }
        lg = a1 + fcb[r1]; outp[r1] = lg;
        if (lg > best) { best = lg; bbi = r1; }
        lg = a2 + fcb[r2]; outp[r2] = lg;
        if (lg > best) { best = lg; bbi = r2; }
        if (v3) {
            lg = a3 + fcb[r3]; outp[r3] = lg;
            if (lg > best) { best = lg; bbi = r3; }
        }
        s_wval[wv] = best; s_widx[wv] = bbi;
    }
    __syncthreads();

    if (tid == 0) {
        float bv = -FLT_MAX; int bi = 0x7fffffff;
#pragma unroll
        for (int k = 0; k < 16; ++k) {
            float v = s_wval[k]; int id = s_widx[k];
            if (v > bv || (v == bv && id < bi)) { bv = v; bi = id; }
        }
        pval[bid] = bv;
        pidx[bid] = bi;
    }
}

extern "C" void kernel_launch(void* const* d_in, const int* in_sizes, int n_in,
                              void* d_out, int out_size, void* d_ws, size_t ws_size,
                              hipStream_t stream) {
    const float* z   = (const float*)d_in[0];
    const float* c   = (const float*)d_in[1];
    const float* l1W = (const float*)d_in[2];
    const float* l1b = (const float*)d_in[3];
    const float* emb = (const float*)d_in[4];
    const float* Wih = (const float*)d_in[5];
    const float* Whh = (const float*)d_in[6];
    const float* bih = (const float*)d_in[7];
    const float* bhh = (const float*)d_in[8];
    const float* fcW = (const float*)d_in[9];
    const float* fcb = (const float*)d_in[10];
    float* out = (float*)d_out;
    float* ws  = (float*)d_ws;

    hipLaunchKernelGGL(k_prologue, dim3(P_BLK), dim3(NTHR), 0, stream,
                       z, c, l1W, l1b, ws);
    for (int t = 0; t < NSTEP; ++t) {
        hipLaunchKernelGGL(k_stepA, dim3(A_BLK), dim3(NTHR), 0, stream,
                           emb, Wih, Whh, bih, bhh, ws, t);
        hipLaunchKernelGGL(k_stepB, dim3(B_BLK), dim3(NTHR), 0, stream,
                           fcW, fcb, ws, out, t);
    }
}

// Round 8
// 4630.544 us; speedup vs baseline: 4.2078x; 1.0181x over previous
//
#include <hip/hip_runtime.h>
#include <float.h>
#include <math.h>

#define H      1024     // LATENT
#define V      32000    // VOCAB
#define NCOND  64
#define NLIN   1024
#define ZCN    1088     // LIN + COND
#define NSTEP  128

#define NTHR   1024
#define P_BLK  64       // prologue: 1024 waves (one per h0 row)
#define R_BLK  256      // k_prep:   4096 waves (one per rww row)
#define A_BLK  256      // stepA:    4096 waves (one per gate row)
#define B_BLK  512      // stepB:    8192 waves (4 fc rows each)

#define DOT4(a,b) ((a).x*(b).x + (a).y*(b).y + (a).z*(b).z + (a).w*(b).w)

// ws layout (floats):
//   [0, H)          h       (single buffer: A(t) overwrites after B(t-1) consumed it)
//   [H, 2H)         cell state c
//   [2H, 2H+512)    pval    per-block argmax val (stepB)
//   [2H+512, 3H)    pidx    per-block argmax idx (int)
//   [3H, 7H)        rww     rww[row] = Whh[row]·h + bih[row] + bhh[row], row in [0,4096)
// Recurrence carried via rww: stepA(t) = Wih·x + rww(h(t-1)); stepB(t) produces
// rww(h(t)) for stepA(t+1); k_prep produces rww(h0).

__device__ __forceinline__ float waveReduceSum(float v) {
#pragma unroll
    for (int off = 32; off > 0; off >>= 1)
        v += __shfl_down(v, off, 64);
    return v;
}

extern "C" __global__ void __launch_bounds__(NTHR)
k_prologue(const float* __restrict__ z, const float* __restrict__ cnd,
           const float* __restrict__ l1W, const float* __restrict__ l1b,
           float* __restrict__ ws)
{
    const int tid  = threadIdx.x;
    const int lane = tid & 63;
    const int wv   = tid >> 6;
    const int g    = blockIdx.x * 16 + wv;      // row in [0, 1024)

    float* hbuf = ws;
    float* cst  = ws + H;
    if (blockIdx.x == 0) cst[tid] = 0.f;        // zero cell state

    const float* wr = l1W + (size_t)g * ZCN;
    float acc = 0.f;
    for (int k = lane; k < ZCN; k += 64) {
        float zc = (k < NLIN) ? z[k] : cnd[k - NLIN];
        acc += wr[k] * zc;
    }
    acc = waveReduceSum(acc);
    if (lane == 0) hbuf[g] = acc + l1b[g];
}

// rww(h0) — one wave per row, h0 staged in LDS
extern "C" __global__ void __launch_bounds__(NTHR)
k_prep(const float* __restrict__ Whh, const float* __restrict__ bih,
       const float* __restrict__ bhh, float* __restrict__ ws)
{
    __shared__ __align__(16) float s_h[H];
    const int tid  = threadIdx.x;
    const int lane = tid & 63;
    const int wv   = tid >> 6;
    const int row  = blockIdx.x * 16 + wv;      // [0, 4096)

    float* rww = ws + 3 * H;
    s_h[tid] = ws[tid];
    __syncthreads();

    const float4* wr = (const float4*)(Whh + (size_t)row * H);
    const float4* hv = (const float4*)s_h;
    float acc = 0.f;
#pragma unroll
    for (int k = 0; k < 4; ++k) {
        const int idx = (k << 6) + lane;
        acc += DOT4(wr[idx], hv[idx]);
    }
    acc = waveReduceSum(acc);
    if (lane == 0) rww[row] = acc + bih[row] + bhh[row];
}

extern "C" __global__ void __launch_bounds__(NTHR)
k_stepA(const float* __restrict__ emb, const float* __restrict__ Wih,
        float* __restrict__ ws, int t)
{
    __shared__ __align__(16) float s_x[H];
    __shared__ float s_gate[16];
    __shared__ int   s_tok;

    const int tid  = threadIdx.x;
    const int lane = tid & 63;
    const int wv   = tid >> 6;
    const int bid  = blockIdx.x;

    float* hbuf = ws;
    float* cst  = ws + H;
    float* pval = ws + 2 * H;
    int*   pidx = (int*)(ws + 2 * H + B_BLK);
    float* rww  = ws + 3 * H;

    // wave wv owns gate row: elem = wv>>2, gate = wv&3 (PyTorch i,f,g,o)
    const int elem = wv >> 2;
    const int gate = wv & 3;
    const int hj   = (bid << 2) + elem;
    const int grow = gate * H + hj;

    // ---- prefetch (token-independent): Wih row + rww, issued before resolve ----
    const float4* wr = (const float4*)(Wih + (size_t)grow * H);
    float4 w0 = wr[lane];
    float4 w1 = wr[64 + lane];
    float4 w2 = wr[128 + lane];
    float4 w3 = wr[192 + lane];
    float  rwv = rww[grow];      // same addr across lanes -> broadcast

    // ---- token resolve (redundant per block; partials from stepB(t-1)) ----
    if (t == 0) {
        if (tid == 0) s_tok = 0;                // SOS
    } else if (wv == 0) {
        float bv = -FLT_MAX; int bi = 0x7fffffff;
        for (int k = lane; k < B_BLK; k += 64) {          // 8 entries/lane, ascending
            float v = pval[k]; int id = pidx[k];
            if (v > bv || (v == bv && id < bi)) { bv = v; bi = id; }
        }
#pragma unroll
        for (int off = 32; off > 0; off >>= 1) {
            float ov = __shfl_down(bv, off, 64);
            int   oi = __shfl_down(bi, off, 64);
            if (ov > bv || (ov == bv && oi < bi)) { bv = ov; bi = oi; }
        }
        if (lane == 0) s_tok = bi;
    }
    __syncthreads();

    // ---- stage x = relu(emb[tok]) ----
    {
        const float* er = emb + (size_t)s_tok * H;
        float e = er[tid];
        s_x[tid] = e > 0.f ? e : 0.f;
    }
    __syncthreads();

    // ---- gate = Wih·x (regs ⊙ LDS) + rww (carries Whh·h + biases) ----
    {
        const float4* xv = (const float4*)s_x;
        float acc = DOT4(w0, xv[lane])
                  + DOT4(w1, xv[64 + lane])
                  + DOT4(w2, xv[128 + lane])
                  + DOT4(w3, xv[192 + lane]);
        acc = waveReduceSum(acc);
        if (lane == 0) s_gate[wv] = acc + rwv;
    }
    __syncthreads();

    // ---- fused LSTM cell update for this block's 4 elements ----
    if (tid < 4) {
        float gi = s_gate[(tid << 2) + 0];
        float gf = s_gate[(tid << 2) + 1];
        float gg = s_gate[(tid << 2) + 2];
        float go = s_gate[(tid << 2) + 3];
        float i_ = 1.f / (1.f + expf(-gi));
        float f_ = 1.f / (1.f + expf(-gf));
        float g_ = tanhf(gg);
        float o_ = 1.f / (1.f + expf(-go));
        const int j = (bid << 2) + tid;
        float cn = f_ * cst[j] + i_ * g_;
        cst[j] = cn;
        hbuf[j] = o_ * tanhf(cn);
    }
}

extern "C" __global__ void __launch_bounds__(NTHR)
k_stepB(const float* __restrict__ Whh, const float* __restrict__ bih,
        const float* __restrict__ bhh, const float* __restrict__ fcW,
        const float* __restrict__ fcb, float* __restrict__ ws,
        float* __restrict__ out, int t)
{
    __shared__ __align__(16) float s_h[H];
    __shared__ float s_wval[16];
    __shared__ int   s_widx[16];

    const int tid  = threadIdx.x;
    const int lane = tid & 63;
    const int wv   = tid >> 6;
    const int bid  = blockIdx.x;
    const int w    = bid * 16 + wv;             // wave id in [0, 8192)

    float* pval = ws + 2 * H;
    int*   pidx = (int*)(ws + 2 * H + B_BLK);
    float* rww  = ws + 3 * H;

    s_h[tid] = ws[tid];                          // h(t) from stepA(t)
    __syncthreads();

    const float4* h4p = (const float4*)s_h;
    float4 hb[4];
    hb[0] = h4p[lane];
    hb[1] = h4p[64 + lane];
    hb[2] = h4p[128 + lane];
    hb[3] = h4p[192 + lane];

    float best = -FLT_MAX; int bbi = 0x7fffffff;
    float* outp = out + (size_t)t * V;

    // 4 fc rows per wave: r = w + k*8192; slot 3 may be OOB (V=32000)
    const int r0 = w;
    const int r1 = w + 8192;
    const int r2 = w + 16384;
    const int r3 = w + 24576;
    const bool v3 = (r3 < V);
    const float4* p0 = (const float4*)(fcW + (size_t)r0 * H);
    const float4* p1 = (const float4*)(fcW + (size_t)r1 * H);
    const float4* p2 = (const float4*)(fcW + (size_t)r2 * H);
    const float4* p3 = (const float4*)(fcW + (size_t)(v3 ? r3 : 0) * H);

    // blocks 0..255 also produce one rww row per wave (row = w in [0,4096))
    const bool doR = (bid < 256);
    const float4* pw = doR ? (const float4*)(Whh + (size_t)w * H) : p0;

    float a0 = 0.f, a1 = 0.f, a2 = 0.f, a3 = 0.f, aw = 0.f;
#pragma unroll
    for (int k = 0; k < 4; ++k) {
        const int idx = (k << 6) + lane;
        a0 += DOT4(p0[idx], hb[k]);
        a1 += DOT4(p1[idx], hb[k]);
        a2 += DOT4(p2[idx], hb[k]);
        a3 += DOT4(p3[idx], hb[k]);
        if (doR) aw += DOT4(pw[idx], hb[k]);
    }
#pragma unroll
    for (int off = 32; off > 0; off >>= 1) {
        a0 += __shfl_down(a0, off, 64);
        a1 += __shfl_down(a1, off, 64);
        a2 += __shfl_down(a2, off, 64);
        a3 += __shfl_down(a3, off, 64);
    }
    if (doR) {
        aw = waveReduceSum(aw);
        if (lane == 0) rww[w] = aw + bih[w] + bhh[w];
    }
    if (lane == 0) {
        float lg;
        lg = a0 + fcb[r0]; outp[r0] = lg;
        if (lg > best) { best = lg; bbi = r0; }
        lg = a1 + fcb[r1]; outp[r1] = lg;
        if (lg > best) { best = lg; bbi = r1; }
        lg = a2 + fcb[r2]; outp[r2] = lg;
        if (lg > best) { best = lg; bbi = r2; }
        if (v3) {
            lg = a3 + fcb[r3]; outp[r3] = lg;
            if (lg > best) { best = lg; bbi = r3; }
        }
        s_wval[wv] = best; s_widx[wv] = bbi;
    }
    __syncthreads();

    if (tid == 0) {
        float bv = -FLT_MAX; int bi = 0x7fffffff;
#pragma unroll
        for (int k = 0; k < 16; ++k) {
            float v = s_wval[k]; int id = s_widx[k];
            if (v > bv || (v == bv && id < bi)) { bv = v; bi = id; }
        }
        pval[bid] = bv;
        pidx[bid] = bi;
    }
}

extern "C" void kernel_launch(void* const* d_in, const int* in_sizes, int n_in,
                              void* d_out, int out_size, void* d_ws, size_t ws_size,
                              hipStream_t stream) {
    const float* z   = (const float*)d_in[0];
    const float* c   = (const float*)d_in[1];
    const float* l1W = (const float*)d_in[2];
    const float* l1b = (const float*)d_in[3];
    const float* emb = (const float*)d_in[4];
    const float* Wih = (const float*)d_in[5];
    const float* Whh = (const float*)d_in[6];
    const float* bih = (const float*)d_in[7];
    const float* bhh = (const float*)d_in[8];
    const float* fcW = (const float*)d_in[9];
    const float* fcb = (const float*)d_in[10];
    float* out = (float*)d_out;
    float* ws  = (float*)d_ws;

    hipLaunchKernelGGL(k_prologue, dim3(P_BLK), dim3(NTHR), 0, stream,
                       z, c, l1W, l1b, ws);
    hipLaunchKernelGGL(k_prep, dim3(R_BLK), dim3(NTHR), 0, stream,
                       Whh, bih, bhh, ws);
    for (int t = 0; t < NSTEP; ++t) {
        hipLaunchKernelGGL(k_stepA, dim3(A_BLK), dim3(NTHR), 0, stream,
                           emb, Wih, ws, t);
        hipLaunchKernelGGL(k_stepB, dim3(B_BLK), dim3(NTHR), 0, stream,
                           Whh, bih, bhh, fcW, fcb, ws, out, t);
    }
}